// Round 14
// baseline (225.513 us; speedup 1.0000x reference)
//
#include <hip/hip_runtime.h>
#include <math.h>

// Neural Additive Model: 256 per-feature MLPs 1->128->64->32->1 (ReLU), summed.
// B=8192, fp32 in/out.
//
// Exact rank-table decomposition: pre-relu h2[b,k] = x_b*Sw[r,k] + Sb[r,k],
// r = #(sorted layer-1 thresholds < x_b). Layer 3 on f16 MFMA (A=W3^T, B=h2).
//
// Round 14 (R13 budget: LDS pipe ~32 us of the 55 us kernel is the wall;
// 13 DS instr per 16 elems):
//  * mfma_f32_32x32x16_f16: wave-round = 32 elems, 4 chained K=16 mfmas.
//    Search duplication 4x -> 2x; epilogue 2 shfl -> 1 (lane's 16 C/D regs
//    already span its channel rows: row=(reg&3)+8*(reg>>2)+4*(lane>>5)).
//  * Register-tree binary search for s=64/32/16 (7 thresholds in regs,
//    ~10 VALU): search LDS reads 7 -> 4.
//  * Net: 6.5 DS instr per 16 elems (was 13).

#define NF   256
#define NH1  128
#define NH2  64
#define NH3  32
#define NB   8192

#define NRANK 129
#define ROW4  17                      // uint4 per table row (16 data + 1 pad)
#define ROWH  136                     // halfwords per row

typedef float    f32x16 __attribute__((ext_vector_type(16)));
typedef unsigned u32x4  __attribute__((ext_vector_type(4)));
typedef _Float16 h16x2  __attribute__((ext_vector_type(2)));
typedef _Float16 h16x8  __attribute__((ext_vector_type(8)));

// h2 pair: relu(x*Sw + Sb) on 2 packed f16 channels -> one B-frag dword
__device__ __forceinline__ unsigned pkh2(unsigned sw, unsigned sb, h16x2 xh) {
    h16x2 r = __builtin_elementwise_fma(xh, __builtin_bit_cast(h16x2, sw),
                                            __builtin_bit_cast(h16x2, sb));
    h16x2 hz = {(_Float16)0.f, (_Float16)0.f};
    return __builtin_bit_cast(unsigned, __builtin_elementwise_max(r, hz));
}

__global__ __launch_bounds__(256) void init_out_kernel(float* __restrict__ out,
                                                       const float* __restrict__ bias) {
    int i = blockIdx.x * 256 + threadIdx.x;
    if (i < NB) out[i] = bias[0];
}

// ---------------- fused: build table in LDS, then MFMA main loop ----------------
__global__ __launch_bounds__(1024, 8) void nam_fused(
    const float* __restrict__ x,      // [B][F], strided reads (L3 absorbs reuse)
    const float* __restrict__ W1, const float* __restrict__ b1,
    const float* __restrict__ W2, const float* __restrict__ b2,
    const float* __restrict__ W3, const float* __restrict__ b3,
    const float* __restrict__ W4, const float* __restrict__ b4,
    float* __restrict__ out)
{
    __shared__ u32x4 SP4[NRANK * ROW4];    // 35.1 KB: per row, 32 Sw-pair dwords,
                                           //   32 Sb-pair dwords (f16), 4 pad
    __shared__ float tkey[NH1];            // sorted thresholds
    __shared__ int   tidx[NH1];
    __shared__ float w1s[NH1], b1s[NH1];
    __shared__ float Pbw[8][NH2], Pbb[8][NH2], Pdw[8][NH2], Pdb[8][NH2]; // 8 KB

    const int f    = blockIdx.x >> 1;      // feature
    const int half = blockIdx.x & 1;       // batch half
    const int t = (int)threadIdx.x;
    _Float16* SPh = (_Float16*)SP4;

    // ======== Phase A: build the rank table in LDS (packed f16 pairs) ========
    const float* __restrict__ gw2 = W2 + (size_t)f * NH1 * NH2;
    if (t < NH1) {
        float w  = W1[f * NH1 + t];
        float bb = b1[f * NH1 + t];
        w1s[t] = w; b1s[t] = bb;
        tkey[t] = (w != 0.0f) ? (-bb / w) : INFINITY;   // w==0: never toggled
        tidx[t] = t;
    }
    __syncthreads();

    // bitonic sort of 128 (key asc, payload idx); 64 comparators
    for (int size = 2; size <= NH1; size <<= 1) {
        for (int stride = size >> 1; stride > 0; stride >>= 1) {
            if (t < 64) {
                int pos = ((t / stride) * (stride << 1)) + (t % stride);
                int par = pos + stride;
                bool up = ((pos & size) == 0);
                float a = tkey[pos], c = tkey[par];
                int  ia = tidx[pos], ic = tidx[par];
                if ((a > c) == up) {
                    tkey[pos] = c; tkey[par] = a;
                    tidx[pos] = ic; tidx[par] = ia;
                }
            }
            __syncthreads();
        }
    }

    // chunked scan: 512 threads = (k = t&63) x (chunk c = t>>6, 16 j/ranks each)
    if (t < 512) {
        const int k = t & 63, c = t >> 6;
        float bw = 0.0f, bbp = 0.0f, dw = 0.0f, db = 0.0f;
        #pragma unroll 4
        for (int i = 0; i < 16; ++i) {
            int j = c * 16 + i;    // rank-0 base: w<0 active; w==0&&b>0 const-on
            float w = w1s[j], bv = b1s[j], w2v = gw2[j * NH2 + k];
            if (w < 0.0f) { bw = fmaf(w, w2v, bw); bbp = fmaf(bv, w2v, bbp); }
            else if (w == 0.0f && bv > 0.0f) { bbp = fmaf(bv, w2v, bbp); }
            int jj = tidx[c * 16 + i];   // toggle-delta partial
            float ww = w1s[jj], bv2 = b1s[jj], w2x = gw2[jj * NH2 + k];
            float s = (ww > 0.0f) ? 1.0f : ((ww < 0.0f) ? -1.0f : 0.0f);
            dw = fmaf(s * ww,  w2x, dw);
            db = fmaf(s * bv2, w2x, db);
        }
        Pbw[c][k] = bw; Pbb[c][k] = bbp; Pdw[c][k] = dw; Pdb[c][k] = db;
    }
    __syncthreads();
    if (t < 512) {
        const int k = t & 63, c = t >> 6;
        float accw = 0.0f;
        float accb = b2[f * NH2 + k];    // b2 seed (round-8 lesson)
        #pragma unroll
        for (int c2 = 0; c2 < 8; ++c2) { accw += Pbw[c2][k]; accb += Pbb[c2][k]; }
        for (int c2 = 0; c2 < c; ++c2) { accw += Pdw[c2][k]; accb += Pdb[c2][k]; }
        // layout per row: Sw halves [0..63], Sb halves [64..127], pad to 136
        if (c == 0) {
            SPh[k]      = (_Float16)accw;          // rank-0 row
            SPh[64 + k] = (_Float16)accb;
        }
        #pragma unroll 4
        for (int i = 0; i < 16; ++i) {
            int r = c * 16 + i;
            int j = tidx[r];                       // uniform per chunk -> broadcast
            float w = w1s[j], bv = b1s[j], w2v = gw2[j * NH2 + k];
            float s = (w > 0.0f) ? 1.0f : ((w < 0.0f) ? -1.0f : 0.0f);
            accw = fmaf(s * w,  w2v, accw);
            accb = fmaf(s * bv, w2v, accb);
            SPh[(r + 1) * ROWH + k]      = (_Float16)accw;
            SPh[(r + 1) * ROWH + 64 + k] = (_Float16)accb;
        }
    }
    __syncthreads();

    // ======== Phase B: MFMA main loop, 32x32x16 f16 (A = W3^T, B = h2) ========
    const int lane = t & 63, wv = t >> 6;   // 16 waves
    const int n = lane & 31, q2 = lane >> 5;

    // A-frags: A[m=lane&31][k=(lane>>5)*8+j] = W3[kk][ch=m]; 4 K-tiles of 16
    const float* __restrict__ w3g = W3 + f * NH2 * NH3;
    h16x8 A0, A1, A2, A3;
    #pragma unroll
    for (int j = 0; j < 8; ++j) {
        int kk = q2 * 8 + j;
        A0[j] = (_Float16)w3g[kk * NH3 + n];
        A1[j] = (_Float16)w3g[(kk + 16) * NH3 + n];
        A2[j] = (_Float16)w3g[(kk + 32) * NH3 + n];
        A3[j] = (_Float16)w3g[(kk + 48) * NH3 + n];
    }
    // per-lane channel constants for the 16 C/D rows:
    // row(reg) = (reg&3) + 8*(reg>>2) + 4*q2
    float b3r[16], w4r[16];
    #pragma unroll
    for (int reg = 0; reg < 16; ++reg) {
        int row = (reg & 3) + 8 * (reg >> 2) + 4 * q2;
        b3r[reg] = b3[f * NH3 + row];
        w4r[reg] = W4[f * NH3 + row];
    }
    const float b4f = b4[f];
    // register-tree search levels s=64/32/16 (7 thresholds)
    const float t63 = tkey[63], t31 = tkey[31], t95 = tkey[95];
    const float t15 = tkey[15], t47 = tkey[47], t79 = tkey[79], t111 = tkey[111];

    #pragma unroll 1
    for (int round = 0; round < 8; ++round) {
        const int base = half * 4096 + (round * 16 + wv) * 32;  // 32-elem batch tile
        const float xv = x[(size_t)(base + n) * NF + f];

        // rank = #(tkey < xv): 3 register levels + 4 LDS levels
        int r = (t63 < xv) ? 64 : 0;
        {
            float l1 = (r & 64) ? t95 : t31;
            if (l1 < xv) r += 32;
            float m0 = (r & 64) ? t79  : t15;
            float m1 = (r & 64) ? t111 : t47;
            float l2 = (r & 32) ? m1 : m0;
            if (l2 < xv) r += 16;
        }
        #pragma unroll
        for (int s = 8; s > 0; s >>= 1)
            if (tkey[r + s - 1] < xv) r += s;

        // gather lane's pair-dwords for its column n, row r:
        // Sw uint4 tiles T*2+q2 (T=0..3), Sb at +8
        const int ro = r * ROW4;
        u32x4 SW0 = SP4[ro + q2],      SW1 = SP4[ro + 2 + q2];
        u32x4 SW2 = SP4[ro + 4 + q2],  SW3 = SP4[ro + 6 + q2];
        u32x4 SB0 = SP4[ro + 8 + q2],  SB1 = SP4[ro + 10 + q2];
        u32x4 SB2 = SP4[ro + 12 + q2], SB3 = SP4[ro + 14 + q2];

        // B-frags: one pk_fma + pk_max per 2 channels
        const h16x2 xh = {(_Float16)xv, (_Float16)xv};
        u32x4 d0, d1, d2, d3;
        d0.x = pkh2(SW0.x, SB0.x, xh); d0.y = pkh2(SW0.y, SB0.y, xh);
        d0.z = pkh2(SW0.z, SB0.z, xh); d0.w = pkh2(SW0.w, SB0.w, xh);
        d1.x = pkh2(SW1.x, SB1.x, xh); d1.y = pkh2(SW1.y, SB1.y, xh);
        d1.z = pkh2(SW1.z, SB1.z, xh); d1.w = pkh2(SW1.w, SB1.w, xh);
        d2.x = pkh2(SW2.x, SB2.x, xh); d2.y = pkh2(SW2.y, SB2.y, xh);
        d2.z = pkh2(SW2.z, SB2.z, xh); d2.w = pkh2(SW2.w, SB2.w, xh);
        d3.x = pkh2(SW3.x, SB3.x, xh); d3.y = pkh2(SW3.y, SB3.y, xh);
        d3.z = pkh2(SW3.z, SB3.z, xh); d3.w = pkh2(SW3.w, SB3.w, xh);
        h16x8 B0 = __builtin_bit_cast(h16x8, d0);
        h16x8 B1 = __builtin_bit_cast(h16x8, d1);
        h16x8 B2 = __builtin_bit_cast(h16x8, d2);
        h16x8 B3 = __builtin_bit_cast(h16x8, d3);

        // layer 3: D[ch][batch], fp32 acc seeded with b3 rows
        f32x16 acc;
        #pragma unroll
        for (int reg = 0; reg < 16; ++reg) acc[reg] = b3r[reg];
        acc = __builtin_amdgcn_mfma_f32_32x32x16_f16(A0, B0, acc, 0, 0, 0);
        acc = __builtin_amdgcn_mfma_f32_32x32x16_f16(A1, B1, acc, 0, 0, 0);
        acc = __builtin_amdgcn_mfma_f32_32x32x16_f16(A2, B2, acc, 0, 0, 0);
        acc = __builtin_amdgcn_mfma_f32_32x32x16_f16(A3, B3, acc, 0, 0, 0);

        // layer 4: reduce lane's own 16 channel rows, 1 shfl over q2, 1 atomic
        float p = 0.0f;
        #pragma unroll
        for (int reg = 0; reg < 16; ++reg)
            p = fmaf(fmaxf(acc[reg], 0.0f), w4r[reg], p);
        p += __shfl_xor(p, 32);
        if (lane < 32) atomicAdd(&out[base + lane], p + b4f);
    }
}

extern "C" void kernel_launch(void* const* d_in, const int* in_sizes, int n_in,
                              void* d_out, int out_size, void* d_ws, size_t ws_size,
                              hipStream_t stream) {
    const float* x    = (const float*)d_in[0];
    const float* W1   = (const float*)d_in[1];
    const float* b1   = (const float*)d_in[2];
    const float* W2   = (const float*)d_in[3];
    const float* b2   = (const float*)d_in[4];
    const float* W3   = (const float*)d_in[5];
    const float* b3   = (const float*)d_in[6];
    const float* W4   = (const float*)d_in[7];
    const float* b4   = (const float*)d_in[8];
    const float* bias = (const float*)d_in[9];
    float* out = (float*)d_out;

    // d_out is poisoned before every launch: initialize to bias (atomics add onto it)
    init_out_kernel<<<NB / 256, 256, 0, stream>>>(out, bias);
    // grid 512 = (feature, batch-half): 45.6 KB LDS -> 2 blocks/CU, 32 waves/CU
    nam_fused<<<NF * 2, 1024, 0, stream>>>(x, W1, b1, W2, b2,
                                           W3, b3, W4, b4, out);
}

// Round 15
// 129.761 us; speedup vs baseline: 1.7379x; 1.7379x over previous
//
#include <hip/hip_runtime.h>
#include <math.h>

// Neural Additive Model: 256 per-feature MLPs 1->128->64->32->1 (ReLU), summed.
// B=8192, fp32 in/out.
//
// Exact rank-table decomposition: pre-relu h2[b,k] = x_b*Sw[r,k] + Sb[r,k],
// r = #(sorted layer-1 thresholds < x_b). Layer 3 on f16 MFMA (A=W3^T, B=h2).
//
// Round 15: ONE-LINE fix of R14's spill. launch_bounds(1024,8) capped VGPR at
// 64 while the 32x32-MFMA path needs ~100 live regs (acc16 + A16 + b3/w4 32 +
// gather temps) -> accumulators spilled to scratch -> FETCH 396 MB / WRITE
// 108 MB of pure spill traffic, VALUBusy 11%. Fix: launch_bounds(1024,4)
// (128-VGPR cap). Cost: 1 block/CU (16 waves) instead of 2 -- acceptable,
// the 32x32 shape needs ~40% fewer DS instrs per element than R13's 16x16.
// R14's absmax 0.0156 already proved the 32x32 fragment layouts correct.

#define NF   256
#define NH1  128
#define NH2  64
#define NH3  32
#define NB   8192

#define NRANK 129
#define ROW4  17                      // uint4 per table row (16 data + 1 pad)
#define ROWH  136                     // halfwords per row

typedef float    f32x16 __attribute__((ext_vector_type(16)));
typedef unsigned u32x4  __attribute__((ext_vector_type(4)));
typedef _Float16 h16x2  __attribute__((ext_vector_type(2)));
typedef _Float16 h16x8  __attribute__((ext_vector_type(8)));

// h2 pair: relu(x*Sw + Sb) on 2 packed f16 channels -> one B-frag dword
__device__ __forceinline__ unsigned pkh2(unsigned sw, unsigned sb, h16x2 xh) {
    h16x2 r = __builtin_elementwise_fma(xh, __builtin_bit_cast(h16x2, sw),
                                            __builtin_bit_cast(h16x2, sb));
    h16x2 hz = {(_Float16)0.f, (_Float16)0.f};
    return __builtin_bit_cast(unsigned, __builtin_elementwise_max(r, hz));
}

__global__ __launch_bounds__(256) void init_out_kernel(float* __restrict__ out,
                                                       const float* __restrict__ bias) {
    int i = blockIdx.x * 256 + threadIdx.x;
    if (i < NB) out[i] = bias[0];
}

// ---------------- fused: build table in LDS, then MFMA main loop ----------------
__global__ __launch_bounds__(1024, 4) void nam_fused(
    const float* __restrict__ x,      // [B][F], strided reads (L3 absorbs reuse)
    const float* __restrict__ W1, const float* __restrict__ b1,
    const float* __restrict__ W2, const float* __restrict__ b2,
    const float* __restrict__ W3, const float* __restrict__ b3,
    const float* __restrict__ W4, const float* __restrict__ b4,
    float* __restrict__ out)
{
    __shared__ u32x4 SP4[NRANK * ROW4];    // 35.1 KB: per row, 32 Sw-pair dwords,
                                           //   32 Sb-pair dwords (f16), 4 pad
    __shared__ float tkey[NH1];            // sorted thresholds
    __shared__ int   tidx[NH1];
    __shared__ float w1s[NH1], b1s[NH1];
    __shared__ float Pbw[8][NH2], Pbb[8][NH2], Pdw[8][NH2], Pdb[8][NH2]; // 8 KB

    const int f    = blockIdx.x >> 1;      // feature
    const int half = blockIdx.x & 1;       // batch half
    const int t = (int)threadIdx.x;
    _Float16* SPh = (_Float16*)SP4;

    // ======== Phase A: build the rank table in LDS (packed f16 pairs) ========
    const float* __restrict__ gw2 = W2 + (size_t)f * NH1 * NH2;
    if (t < NH1) {
        float w  = W1[f * NH1 + t];
        float bb = b1[f * NH1 + t];
        w1s[t] = w; b1s[t] = bb;
        tkey[t] = (w != 0.0f) ? (-bb / w) : INFINITY;   // w==0: never toggled
        tidx[t] = t;
    }
    __syncthreads();

    // bitonic sort of 128 (key asc, payload idx); 64 comparators
    for (int size = 2; size <= NH1; size <<= 1) {
        for (int stride = size >> 1; stride > 0; stride >>= 1) {
            if (t < 64) {
                int pos = ((t / stride) * (stride << 1)) + (t % stride);
                int par = pos + stride;
                bool up = ((pos & size) == 0);
                float a = tkey[pos], c = tkey[par];
                int  ia = tidx[pos], ic = tidx[par];
                if ((a > c) == up) {
                    tkey[pos] = c; tkey[par] = a;
                    tidx[pos] = ic; tidx[par] = ia;
                }
            }
            __syncthreads();
        }
    }

    // chunked scan: 512 threads = (k = t&63) x (chunk c = t>>6, 16 j/ranks each)
    if (t < 512) {
        const int k = t & 63, c = t >> 6;
        float bw = 0.0f, bbp = 0.0f, dw = 0.0f, db = 0.0f;
        #pragma unroll 4
        for (int i = 0; i < 16; ++i) {
            int j = c * 16 + i;    // rank-0 base: w<0 active; w==0&&b>0 const-on
            float w = w1s[j], bv = b1s[j], w2v = gw2[j * NH2 + k];
            if (w < 0.0f) { bw = fmaf(w, w2v, bw); bbp = fmaf(bv, w2v, bbp); }
            else if (w == 0.0f && bv > 0.0f) { bbp = fmaf(bv, w2v, bbp); }
            int jj = tidx[c * 16 + i];   // toggle-delta partial
            float ww = w1s[jj], bv2 = b1s[jj], w2x = gw2[jj * NH2 + k];
            float s = (ww > 0.0f) ? 1.0f : ((ww < 0.0f) ? -1.0f : 0.0f);
            dw = fmaf(s * ww,  w2x, dw);
            db = fmaf(s * bv2, w2x, db);
        }
        Pbw[c][k] = bw; Pbb[c][k] = bbp; Pdw[c][k] = dw; Pdb[c][k] = db;
    }
    __syncthreads();
    if (t < 512) {
        const int k = t & 63, c = t >> 6;
        float accw = 0.0f;
        float accb = b2[f * NH2 + k];    // b2 seed (round-8 lesson)
        #pragma unroll
        for (int c2 = 0; c2 < 8; ++c2) { accw += Pbw[c2][k]; accb += Pbb[c2][k]; }
        for (int c2 = 0; c2 < c; ++c2) { accw += Pdw[c2][k]; accb += Pdb[c2][k]; }
        // layout per row: Sw halves [0..63], Sb halves [64..127], pad to 136
        if (c == 0) {
            SPh[k]      = (_Float16)accw;          // rank-0 row
            SPh[64 + k] = (_Float16)accb;
        }
        #pragma unroll 4
        for (int i = 0; i < 16; ++i) {
            int r = c * 16 + i;
            int j = tidx[r];                       // uniform per chunk -> broadcast
            float w = w1s[j], bv = b1s[j], w2v = gw2[j * NH2 + k];
            float s = (w > 0.0f) ? 1.0f : ((w < 0.0f) ? -1.0f : 0.0f);
            accw = fmaf(s * w,  w2v, accw);
            accb = fmaf(s * bv, w2v, accb);
            SPh[(r + 1) * ROWH + k]      = (_Float16)accw;
            SPh[(r + 1) * ROWH + 64 + k] = (_Float16)accb;
        }
    }
    __syncthreads();

    // ======== Phase B: MFMA main loop, 32x32x16 f16 (A = W3^T, B = h2) ========
    const int lane = t & 63, wv = t >> 6;   // 16 waves
    const int n = lane & 31, q2 = lane >> 5;

    // A-frags: A[m=lane&31][k=(lane>>5)*8+j] = W3[kk][ch=m]; 4 K-tiles of 16
    const float* __restrict__ w3g = W3 + f * NH2 * NH3;
    h16x8 A0, A1, A2, A3;
    #pragma unroll
    for (int j = 0; j < 8; ++j) {
        int kk = q2 * 8 + j;
        A0[j] = (_Float16)w3g[kk * NH3 + n];
        A1[j] = (_Float16)w3g[(kk + 16) * NH3 + n];
        A2[j] = (_Float16)w3g[(kk + 32) * NH3 + n];
        A3[j] = (_Float16)w3g[(kk + 48) * NH3 + n];
    }
    // per-lane channel constants for the 16 C/D rows:
    // row(reg) = (reg&3) + 8*(reg>>2) + 4*q2
    float b3r[16], w4r[16];
    #pragma unroll
    for (int reg = 0; reg < 16; ++reg) {
        int row = (reg & 3) + 8 * (reg >> 2) + 4 * q2;
        b3r[reg] = b3[f * NH3 + row];
        w4r[reg] = W4[f * NH3 + row];
    }
    const float b4f = b4[f];
    // register-tree search levels s=64/32/16 (7 thresholds)
    const float t63 = tkey[63], t31 = tkey[31], t95 = tkey[95];
    const float t15 = tkey[15], t47 = tkey[47], t79 = tkey[79], t111 = tkey[111];

    #pragma unroll 1
    for (int round = 0; round < 8; ++round) {
        const int base = half * 4096 + (round * 16 + wv) * 32;  // 32-elem batch tile
        const float xv = x[(size_t)(base + n) * NF + f];

        // rank = #(tkey < xv): 3 register levels + 4 LDS levels
        int r = (t63 < xv) ? 64 : 0;
        {
            float l1 = (r & 64) ? t95 : t31;
            if (l1 < xv) r += 32;
            float m0 = (r & 64) ? t79  : t15;
            float m1 = (r & 64) ? t111 : t47;
            float l2 = (r & 32) ? m1 : m0;
            if (l2 < xv) r += 16;
        }
        #pragma unroll
        for (int s = 8; s > 0; s >>= 1)
            if (tkey[r + s - 1] < xv) r += s;

        // gather lane's pair-dwords for its column n, row r:
        // Sw uint4 tiles T*2+q2 (T=0..3), Sb at +8
        const int ro = r * ROW4;
        u32x4 SW0 = SP4[ro + q2],      SW1 = SP4[ro + 2 + q2];
        u32x4 SW2 = SP4[ro + 4 + q2],  SW3 = SP4[ro + 6 + q2];
        u32x4 SB0 = SP4[ro + 8 + q2],  SB1 = SP4[ro + 10 + q2];
        u32x4 SB2 = SP4[ro + 12 + q2], SB3 = SP4[ro + 14 + q2];

        // B-frags: one pk_fma + pk_max per 2 channels
        const h16x2 xh = {(_Float16)xv, (_Float16)xv};
        u32x4 d0, d1, d2, d3;
        d0.x = pkh2(SW0.x, SB0.x, xh); d0.y = pkh2(SW0.y, SB0.y, xh);
        d0.z = pkh2(SW0.z, SB0.z, xh); d0.w = pkh2(SW0.w, SB0.w, xh);
        d1.x = pkh2(SW1.x, SB1.x, xh); d1.y = pkh2(SW1.y, SB1.y, xh);
        d1.z = pkh2(SW1.z, SB1.z, xh); d1.w = pkh2(SW1.w, SB1.w, xh);
        d2.x = pkh2(SW2.x, SB2.x, xh); d2.y = pkh2(SW2.y, SB2.y, xh);
        d2.z = pkh2(SW2.z, SB2.z, xh); d2.w = pkh2(SW2.w, SB2.w, xh);
        d3.x = pkh2(SW3.x, SB3.x, xh); d3.y = pkh2(SW3.y, SB3.y, xh);
        d3.z = pkh2(SW3.z, SB3.z, xh); d3.w = pkh2(SW3.w, SB3.w, xh);
        h16x8 B0 = __builtin_bit_cast(h16x8, d0);
        h16x8 B1 = __builtin_bit_cast(h16x8, d1);
        h16x8 B2 = __builtin_bit_cast(h16x8, d2);
        h16x8 B3 = __builtin_bit_cast(h16x8, d3);

        // layer 3: D[ch][batch], fp32 acc seeded with b3 rows
        f32x16 acc;
        #pragma unroll
        for (int reg = 0; reg < 16; ++reg) acc[reg] = b3r[reg];
        acc = __builtin_amdgcn_mfma_f32_32x32x16_f16(A0, B0, acc, 0, 0, 0);
        acc = __builtin_amdgcn_mfma_f32_32x32x16_f16(A1, B1, acc, 0, 0, 0);
        acc = __builtin_amdgcn_mfma_f32_32x32x16_f16(A2, B2, acc, 0, 0, 0);
        acc = __builtin_amdgcn_mfma_f32_32x32x16_f16(A3, B3, acc, 0, 0, 0);

        // layer 4: reduce lane's own 16 channel rows, 1 shfl over q2, 1 atomic
        float p = 0.0f;
        #pragma unroll
        for (int reg = 0; reg < 16; ++reg)
            p = fmaf(fmaxf(acc[reg], 0.0f), w4r[reg], p);
        p += __shfl_xor(p, 32);
        if (lane < 32) atomicAdd(&out[base + lane], p + b4f);
    }
}

extern "C" void kernel_launch(void* const* d_in, const int* in_sizes, int n_in,
                              void* d_out, int out_size, void* d_ws, size_t ws_size,
                              hipStream_t stream) {
    const float* x    = (const float*)d_in[0];
    const float* W1   = (const float*)d_in[1];
    const float* b1   = (const float*)d_in[2];
    const float* W2   = (const float*)d_in[3];
    const float* b2   = (const float*)d_in[4];
    const float* W3   = (const float*)d_in[5];
    const float* b3   = (const float*)d_in[6];
    const float* W4   = (const float*)d_in[7];
    const float* b4   = (const float*)d_in[8];
    const float* bias = (const float*)d_in[9];
    float* out = (float*)d_out;

    // d_out is poisoned before every launch: initialize to bias (atomics add onto it)
    init_out_kernel<<<NB / 256, 256, 0, stream>>>(out, bias);
    // grid 512 = (feature, batch-half)
    nam_fused<<<NF * 2, 1024, 0, stream>>>(x, W1, b1, W2, b2,
                                           W3, b3, W4, b4, out);
}